// Round 19
// baseline (144.061 us; speedup 1.0000x reference)
//
#include <hip/hip_runtime.h>

// LIF neuron forward, v13: TWO consumer waves on the SAME SIMD (w0,w4) so
// their round-robin issue fills each other's dependency stalls.
// V = leak*V + I; spike = (V >= 1); V -= spike.
// current: [B=8, S=4096, D=1024] f32, membrane: [B, D] f32.
// Outputs concatenated: spikes [B,S,D] then mem_final [B,D], all f32.
//
// Evidence r5-r18: single-chain cadence 43-44cy/step, invariant to
// everything EXCEPT consumer-SIMD conditions; v11/v12 asm variants hit the
// VALU->SGPR->writelane hazard (+5 waitstates x2/step). v13 keeps v10's
// proven vcc-only consumer (44cy solo) and adds TLP on the consumer SIMD:
// 8-wave block, waves 0,4 (both SIMD0 by i%4 assignment) each run 16
// channels' chains; gaps fill -> cadence ~28-30cy. Grid stays 256 blocks
// (CPB=32). w1/w5 producers, w2/w3/w6/w7 writers.
//
// Numerics (validated r5-r18, absmax 7.6e-6): forward spike == hard
// threshold exactly in fp32; fp contract(off) pins mul-then-add rounding;
// mem = f ? (v-1) : v bit-identical to v - spike.

#define LIF_B 8
#define LIF_S 4096
#define LIF_D 1024
#define CHUNK 256
#define NH    (LIF_S / CHUNK)   // 16
#define CPB   32                // channels per block

typedef __attribute__((address_space(3))) unsigned int lds_uint;
typedef const __attribute__((address_space(1))) unsigned int glb_uint;

__global__ __launch_bounds__(512, 1) void lif_v13_kernel(
    const float* __restrict__ current,
    const float* __restrict__ membrane,
    float* __restrict__ spikes,
    float* __restrict__ mem_out)
{
    #pragma clang fp contract(off)

    __shared__ __align__(16) float in_ring[2][CHUNK][CPB];   // 64 KB
    __shared__ unsigned mask_lds[2][8][CPB];                 // 2 KB spike bits

    const int wid  = threadIdx.x >> 6;   // 0,4=consumers 1,5=producers rest=writers
    const int lane = threadIdx.x & 63;
    const int blk  = blockIdx.x;         // 0..255
    const int bb   = blk >> 5;           // batch (1024/32 = 32 ch-blocks)
    const int ch0  = (blk & 31) * CPB;

    const float* gwin  = current + (size_t)bb * LIF_S * LIF_D + ch0;
    float*       sbase = spikes  + (size_t)bb * LIF_S * LIF_D + ch0;

    const int prow = lane >> 3;          // producer 8-row mapping
    const int pcol = (lane & 7) * 4;
    const int lx   = lane & 15;

    const bool is_cons = (wid == 0) || (wid == 4);
    const bool is_prod = (wid == 1) || (wid == 5);
    const int  co      = (wid == 4) ? 16 : 0;          // consumer ch offset
    const int  phalf   = (wid == 5) ? 1 : 0;           // producer row half
    // writer index 0..3 for wid 2,3,6,7
    const int  wi      = (wid == 2) ? 0 : (wid == 3) ? 1 : (wid == 6) ? 2 : 3;

    float mem = 0.0f;

    // ---- prologue: producers stage chunk 0; consumers load membrane ----
    if (is_prod) {
        #pragma unroll
        for (int f = 0; f < 16; ++f) {
            const float* src = gwin
                + (size_t)(phalf * 128 + 8 * f + prow) * LIF_D + pcol;
            __builtin_amdgcn_global_load_lds(
                (glb_uint*)(const void*)src,
                (lds_uint*)(void*)(&in_ring[0][0][0]
                                   + (size_t)(phalf * 16 + f) * 256), 16, 0, 0);
        }
        asm volatile("s_waitcnt vmcnt(0)" ::: "memory");
    } else if (is_cons) {
        mem = membrane[bb * LIF_D + ch0 + co + lx];
    }
    __builtin_amdgcn_s_barrier();
    asm volatile("" ::: "memory");

    for (int h = 0; h < NH; ++h) {
        if (is_cons) {
            // ---- consumer: v10's exact inner loop, 16 channels/wave ----
            const float* ib = &in_ring[h & 1][0][co + lx];
            unsigned m[8];
            #pragma unroll
            for (int j = 0; j < 8; ++j) m[j] = 0u;

            float A[16], Bv[16];
            #pragma unroll
            for (int j = 0; j < 16; ++j) A[j]  = ib[j * CPB];
            #pragma unroll
            for (int j = 0; j < 16; ++j) Bv[j] = ib[(16 + j) * CPB];

            #pragma unroll
            for (int b = 0; b < 16; ++b) {
                const int wd = b >> 1;          // mask word (static)
                const int sh = (b & 1) * 16;    // bit base (static)
                #pragma unroll
                for (int j = 0; j < 16; ++j) {
                    const float c = ((b & 1) == 0) ? A[j] : Bv[j];  // static
                    const float v = 0.9f * mem + c;   // mul-then-add
                    const float w = v - 1.0f;         // off chain
                    const bool  f = (v >= 1.0f);
                    m[wd] |= f ? (1u << (sh + j)) : 0u;
                    mem = f ? w : v;                  // soft reset
                }
                if (b + 2 < 16) {                     // prefetch batch b+2
                    #pragma unroll
                    for (int j = 0; j < 16; ++j) {
                        if ((b & 1) == 0) A[j]  = ib[((b + 2) * 16 + j) * CPB];
                        else              Bv[j] = ib[((b + 2) * 16 + j) * CPB];
                    }
                }
            }

            if (lane < 16) {
                #pragma unroll
                for (int j = 0; j < 8; ++j)
                    mask_lds[h & 1][j][co + lane] = m[j];
            }
            asm volatile("s_waitcnt lgkmcnt(0)" ::: "memory");
        } else if (is_prod) {
            // ---- producers: stage chunk h+1 (half each) ----
            if (h + 1 < NH) {
                const int tb = (h + 1) * CHUNK;
                #pragma unroll
                for (int f = 0; f < 16; ++f) {
                    const float* src = gwin
                        + (size_t)(tb + phalf * 128 + 8 * f + prow) * LIF_D + pcol;
                    __builtin_amdgcn_global_load_lds(
                        (glb_uint*)(const void*)src,
                        (lds_uint*)(void*)(&in_ring[(h + 1) & 1][0][0]
                                           + (size_t)(phalf * 16 + f) * 256),
                        16, 0, 0);
                }
                asm volatile("s_waitcnt vmcnt(0)" ::: "memory");
            }
        } else {
            // ---- writers: expand masks of phase h-1 -> float4 stores ----
            if (h >= 1) {
                const int ph = (h - 1) & 1;
                const int tb = (h - 1) * CHUNK;
                const int whalf = lane >> 5;          // 0/1
                const int wIdx  = 2 * wi + whalf;     // mask word 0..7
                const int c4    = lane & 7;           // float4 col group
                const int rsub  = (lane >> 3) & 3;    // row sub-group
                const int rb    = wi * 64 + whalf * 32;
                unsigned M[4];
                #pragma unroll
                for (int c = 0; c < 4; ++c)
                    M[c] = mask_lds[ph][wIdx][4 * c4 + c];
                #pragma unroll
                for (int k = 0; k < 8; ++k) {
                    const int rloc = rsub * 8 + k;    // row&31
                    const int row  = rb + rloc;
                    float4 vv;
                    vv.x = (float)((M[0] >> rloc) & 1u);
                    vv.y = (float)((M[1] >> rloc) & 1u);
                    vv.z = (float)((M[2] >> rloc) & 1u);
                    vv.w = (float)((M[3] >> rloc) & 1u);
                    *(float4*)(sbase + (size_t)(tb + row) * LIF_D + 4 * c4) = vv;
                }
                asm volatile("s_waitcnt lgkmcnt(0)" ::: "memory");
            }
        }
        __builtin_amdgcn_s_barrier();
        asm volatile("" ::: "memory");
    }

    // ---- epilogue: flush masks of phase NH-1; store final membrane ----
    if (!is_cons && !is_prod) {
        const int ph = (NH - 1) & 1;
        const int tb = (NH - 1) * CHUNK;
        const int whalf = lane >> 5;
        const int wIdx  = 2 * wi + whalf;
        const int c4    = lane & 7;
        const int rsub  = (lane >> 3) & 3;
        const int rb    = wi * 64 + whalf * 32;
        unsigned M[4];
        #pragma unroll
        for (int c = 0; c < 4; ++c)
            M[c] = mask_lds[ph][wIdx][4 * c4 + c];
        #pragma unroll
        for (int k = 0; k < 8; ++k) {
            const int rloc = rsub * 8 + k;
            const int row  = rb + rloc;
            float4 vv;
            vv.x = (float)((M[0] >> rloc) & 1u);
            vv.y = (float)((M[1] >> rloc) & 1u);
            vv.z = (float)((M[2] >> rloc) & 1u);
            vv.w = (float)((M[3] >> rloc) & 1u);
            *(float4*)(sbase + (size_t)(tb + row) * LIF_D + 4 * c4) = vv;
        }
    } else if (is_cons && lane < 16) {
        mem_out[bb * LIF_D + ch0 + co + lane] = mem;
    }
}

extern "C" void kernel_launch(void* const* d_in, const int* in_sizes, int n_in,
                              void* d_out, int out_size, void* d_ws, size_t ws_size,
                              hipStream_t stream) {
    const float* current  = (const float*)d_in[0];   // [8, 4096, 1024]
    const float* membrane = (const float*)d_in[1];   // [8, 1024]

    float* spikes  = (float*)d_out;                                 // [8,4096,1024]
    float* mem_out = (float*)d_out + (size_t)LIF_B * LIF_S * LIF_D; // [8,1024]

    dim3 block(512);                   // 8 waves: w0/w4 consumers (same SIMD),
    dim3 grid(LIF_B * LIF_D / CPB);    //   w1/w5 producers, w2/w3/w6/w7 writers

    hipLaunchKernelGGL(lif_v13_kernel, grid, block, 0, stream,
                       current, membrane, spikes, mem_out);
}